// Round 14
// baseline (66.663 us; speedup 1.0000x reference)
//
#include <hip/hip_runtime.h>
#include <hip/hip_bf16.h>

#define E_N 4
#define B_N 64
#define IN_N 4096
#define H_N 4096
#define R_N 512
#define OUT_N 4096
#define TOT_N 8388608  // R*IN + H*R + R*H + OUT*R

typedef float f32x4 __attribute__((ext_vector_type(4)));
typedef short bf16x8 __attribute__((ext_vector_type(8)));
typedef unsigned short u16x8 __attribute__((ext_vector_type(8)));

__device__ __forceinline__ unsigned short f2bf_bits(float f) {
    return __builtin_bit_cast(unsigned short, __float2bfloat16(f));
}
__device__ __forceinline__ float bfbits2f(unsigned short u) {
    return __builtin_bit_cast(float, ((unsigned)u) << 16);
}

__device__ __forceinline__ void stage16(const void* g, void* l) {
    __builtin_amdgcn_global_load_lds(
        (const __attribute__((address_space(1))) void*)g,
        (__attribute__((address_space(3))) void*)l, 16, 0, 0);
}

// ============ gemm16: no-split-K thin GEMM for L1/L3 (N=512 out) ============
// H[e,b,n] = bf16( sum_k A[b,k] * (W[n,k]+D[e,n,k]) ), K_TOT=4096.
// Block = 16 b-rows x 16 n-cols, full K. Grid 512 = 4e x 32nt x 4bt.
// XCD swizzle: lid=(bid&7)*64+bid>>3 puts the 4 bt-siblings (which share W/D
// rows) on the same XCD -> 3 of 4 W/D reads are L2 hits (cache-coop bet).
// Each wave accumulates k-quarter w; 4-way LDS reduce (w ascending, fixed
// order -> deterministic). No partials, no reduce kernel.
template<int K_TOT, bool CONV_A, bool A_SHARED>
__global__ __launch_bounds__(256, 4)
void gemm16(const __hip_bfloat16* __restrict__ A, const float* __restrict__ AF,
            const float* __restrict__ W, const float* __restrict__ D,
            __hip_bfloat16* __restrict__ OutB)
{
    constexpr int KK = 128;
    constexpr int NTILES = K_TOT / KK;   // 32
    constexpr int BUFSZ = 20480;         // Wt 8K | Dt 8K | At 4K
    __shared__ __align__(16) char smem[2 * BUFSZ];   // 40 KB -> 4 blocks/CU

    const int bid = blockIdx.x;
    const int lid = (bid & 7) * 64 + (bid >> 3);   // XCD-grouped logical id
    const int bt = lid & 3;
    const int nt = (lid >> 2) & 31;
    const int e  = lid >> 7;
    const int tid = threadIdx.x;
    const int l  = tid & 63;
    const int w  = tid >> 6;

    const char* Wb = (const char*)(W + (size_t)(nt * 16) * K_TOT);
    const char* Db = (const char*)(D + (size_t)e * TOT_N + (size_t)(nt * 16) * K_TOT);
    const char* Ab = CONV_A ? nullptr
        : (const char*)(A + (A_SHARED ? (size_t)0 : (size_t)e * B_N * K_TOT)
                          + (size_t)(bt * 16) * K_TOT);
    const char* AFb = CONV_A
        ? (const char*)(AF + (A_SHARED ? (size_t)0 : (size_t)e * B_N * K_TOT)
                           + (size_t)(bt * 16) * K_TOT)
        : nullptr;

    // 20 1-KB chunks/tile: q 0-7 W, 8-15 D, 16-19 A.  q = w + 4i (i=4 <=> A).
    const char* gsrc[5];
    int loff[5], lws[5], kstep[5];
    #pragma unroll
    for (int i = 0; i < 5; ++i) {
        const int q = w + i * 4;
        if (q < 8) {
            const int off = q * 1024 + l * 16;
            const int row = off >> 9, kb = off & 511;   // 512 B per f32 row of 128
            gsrc[i] = Wb + (size_t)row * K_TOT * 4 + (kb ^ ((row & 7) << 4));
            loff[i] = q * 1024; kstep[i] = 512;
        } else if (q < 16) {
            const int c = q - 8;
            const int off = c * 1024 + l * 16;
            const int row = off >> 9, kb = off & 511;
            gsrc[i] = Db + (size_t)row * K_TOT * 4 + (kb ^ ((row & 7) << 4));
            loff[i] = 8192 + c * 1024; kstep[i] = 512;
        } else {
            const int c = q - 16;
            const int off = c * 1024 + l * 16;
            const int row = off >> 8, kb = off & 255;   // 256 B per bf16 row of 128
            if (CONV_A) {
                gsrc[i] = AFb + (size_t)row * K_TOT * 4 + kb * 2;
                lws[i]  = 16384 + (off & ~255) + (kb ^ ((row & 7) << 4));
                kstep[i] = 512;
            } else {
                gsrc[i] = Ab + (size_t)row * K_TOT * 2 + (kb ^ ((row & 7) << 4));
                loff[i] = 16384 + c * 1024; kstep[i] = 256;
            }
        }
    }

    auto stage_all = [&](int t, char* b) {
        #pragma unroll
        for (int i = 0; i < 5; ++i) {
            const char* s = gsrc[i] + (size_t)t * kstep[i];
            if (CONV_A && i == 4) {
                f32x4 a0 = *(const f32x4*)(s);
                f32x4 a1 = *(const f32x4*)(s + 16);
                u16x8 o;
                #pragma unroll
                for (int j = 0; j < 4; ++j) {
                    o[j]     = f2bf_bits(a0[j]);
                    o[j + 4] = f2bf_bits(a1[j]);
                }
                *(u16x8*)(b + lws[i]) = o;
            } else {
                stage16(s, b + loff[i]);
            }
        }
    };

    // fragment addressing (wave w owns k-quarter w of each 128-k tile)
    const int fr  = l & 15;          // A b-row / W n-row == output col
    const int kg  = l >> 4;          // k-subgroup
    const int swz = (fr & 7) << 4;
    const int aoff  = fr * 256 + ((w * 64 + kg * 16) ^ swz);
    const int woffA = fr * 512 + ((w * 128 + kg * 32) ^ swz);
    const int woffB = fr * 512 + (((w * 128 + kg * 32) + 16) ^ swz);

    f32x4 acc = {};
    stage_all(0, smem);
    __syncthreads();

    for (int t = 0; t < NTILES; ++t) {
        if (t + 1 < NTILES)
            stage_all(t + 1, smem + ((t + 1) & 1) * BUFSZ);

        const char* buf = smem + (t & 1) * BUFSZ;
        bf16x8 af = *(const bf16x8*)(buf + 16384 + aoff);
        f32x4 w0 = *(const f32x4*)(buf + woffA);
        f32x4 w1 = *(const f32x4*)(buf + woffB);
        f32x4 d0 = *(const f32x4*)(buf + 8192 + woffA);
        f32x4 d1 = *(const f32x4*)(buf + 8192 + woffB);
        f32x4 s0 = w0 + d0;
        f32x4 s1 = w1 + d1;
        bf16x8 bhi, blo;
        #pragma unroll
        for (int j = 0; j < 4; ++j) {
            unsigned short h0 = f2bf_bits(s0[j]);
            bhi[j] = (short)h0;
            blo[j] = (short)f2bf_bits(s0[j] - bfbits2f(h0));
            unsigned short h1 = f2bf_bits(s1[j]);
            bhi[j + 4] = (short)h1;
            blo[j + 4] = (short)f2bf_bits(s1[j] - bfbits2f(h1));
        }
        acc = __builtin_amdgcn_mfma_f32_16x16x32_bf16(af, bhi, acc, 0, 0, 0);
        acc = __builtin_amdgcn_mfma_f32_16x16x32_bf16(af, blo, acc, 0, 0, 0);
        __syncthreads();
    }

    // 4-way cross-wave k-reduce (w ascending -> deterministic), then write.
    *(f32x4*)(smem + tid * 16) = acc;
    __syncthreads();
    if (w == 0) {
        f32x4 s = {};
        #pragma unroll
        for (int wv = 0; wv < 4; ++wv)
            s += *(const f32x4*)(smem + (wv * 64 + l) * 16);
        #pragma unroll
        for (int i = 0; i < 4; ++i) {
            const int row = bt * 16 + kg * 4 + i;    // C/D: col=l&15, row=kg*4+i
            const int col = nt * 16 + fr;
            OutB[(size_t)e * B_N * R_N + (size_t)row * R_N + col] = __float2bfloat16(s[i]);
        }
    }
}

// ============ R12 gemm_layer (L2/L4 only, verified 48.5 us) ============
template<int K_TOT, int N_TOT, int KS, bool A_SHARED, bool RELU, bool OUT_BF16,
         bool CONV_A>
__global__ __launch_bounds__(256, 2)
void gemm_layer(const __hip_bfloat16* __restrict__ A, const float* __restrict__ AF,
                const float* __restrict__ W, const float* __restrict__ D,
                float* __restrict__ OutF, __hip_bfloat16* __restrict__ OutB)
{
    constexpr int KCH = K_TOT / KS;
    constexpr int NT = N_TOT / 32;
    constexpr int NTILES = KCH / 64;
    constexpr int BUFSZ = 24576;
    __shared__ __align__(16) char smem[2 * BUFSZ];

    const int bid = blockIdx.x;
    const int ks = bid % KS;
    const int nt = (bid / KS) % NT;
    const int e  = bid / (KS * NT);
    const int tid = threadIdx.x;
    const int l  = tid & 63;
    const int w  = tid >> 6;
    const int wn = w & 1;
    const int wm = w >> 1;
    const int lr = l & 15;
    const int lk = (l >> 4) << 3;

    const float* Wb = W + (size_t)(nt * 32) * K_TOT + ks * KCH;
    const float* Db = D + (size_t)e * TOT_N + (size_t)(nt * 32) * K_TOT + ks * KCH;
    const __hip_bfloat16* Ab = A ? (A + (A_SHARED ? (size_t)0 : (size_t)e * B_N * K_TOT)
                                      + ks * KCH) : nullptr;
    const float* AFb = AF ? (AF + (A_SHARED ? (size_t)0 : (size_t)e * B_N * K_TOT)
                                + ks * KCH) : nullptr;

    const char* gsrc[6];
    int loff[6], lws[6], kstep[6];
    #pragma unroll
    for (int i = 0; i < 6; ++i) {
        const int q = w + i * 4;
        if (q < 8) {
            const int off = q * 1024 + l * 16;
            const int row = off >> 8, kb = off & 255;
            gsrc[i] = (const char*)(Wb + (size_t)row * K_TOT) + (kb ^ ((row & 7) << 4));
            loff[i] = q * 1024; kstep[i] = 4;
        } else if (q < 16) {
            const int c = q - 8;
            const int off = c * 1024 + l * 16;
            const int row = off >> 8, kb = off & 255;
            gsrc[i] = (const char*)(Db + (size_t)row * K_TOT) + (kb ^ ((row & 7) << 4));
            loff[i] = 8192 + c * 1024; kstep[i] = 4;
        } else {
            const int c = q - 16;
            const int off = c * 1024 + l * 16;
            const int row = off >> 7, kb = off & 127;
            if (CONV_A) {
                gsrc[i] = (const char*)(AFb + (size_t)row * K_TOT) + kb * 2;
                lws[i]  = 16384 + (off & ~127) + (kb ^ ((row & 7) << 4));
                kstep[i] = 4;
            } else {
                gsrc[i] = (const char*)(Ab + (size_t)row * K_TOT) + (kb ^ ((row & 7) << 4));
                loff[i] = 16384 + c * 1024; kstep[i] = 2;
            }
        }
    }

    auto stage_all = [&](int kk, char* b) {
        #pragma unroll
        for (int i = 0; i < 6; ++i) {
            if (CONV_A && i >= 4) {
                const char* src = gsrc[i] + (size_t)kk * 4;
                f32x4 a0 = *(const f32x4*)(src);
                f32x4 a1 = *(const f32x4*)(src + 16);
                u16x8 o;
                #pragma unroll
                for (int j = 0; j < 4; ++j) {
                    o[j]     = f2bf_bits(a0[j]);
                    o[j + 4] = f2bf_bits(a1[j]);
                }
                *(u16x8*)(b + lws[i]) = o;
            } else {
                stage16(gsrc[i] + (size_t)kk * kstep[i], b + loff[i]);
            }
        }
    };

    f32x4 acc[2] = {};
    const int wrow = wn * 16 + lr;
    const int wswz = (wrow & 7) << 4;
    const int arow0 = wm * 32 + lr;
    const int aswz = (arow0 & 7) << 4;

    stage_all(0, smem);
    __syncthreads();

    for (int t = 0; t < NTILES; ++t) {
        if (t + 1 < NTILES)
            stage_all((t + 1) * 64, smem + ((t + 1) & 1) * BUFSZ);

        const char* buf = smem + (t & 1) * BUFSZ;
        #pragma unroll
        for (int inner = 0; inner < 2; ++inner) {
            const int b0 = (inner * 32 + lk) * 4;
            const char* wrp = buf + wrow * 256;
            const char* drp = buf + 8192 + wrow * 256;
            f32x4 w0 = *(const f32x4*)(wrp + ((b0)      ^ wswz));
            f32x4 w1 = *(const f32x4*)(wrp + ((b0 + 16) ^ wswz));
            f32x4 d0 = *(const f32x4*)(drp + ((b0)      ^ wswz));
            f32x4 d1 = *(const f32x4*)(drp + ((b0 + 16) ^ wswz));
            f32x4 s0 = w0 + d0;
            f32x4 s1 = w1 + d1;
            bf16x8 bhi, blo;
            #pragma unroll
            for (int j = 0; j < 4; ++j) {
                unsigned short h0 = f2bf_bits(s0[j]);
                bhi[j] = (short)h0;
                blo[j] = (short)f2bf_bits(s0[j] - bfbits2f(h0));
                unsigned short h1 = f2bf_bits(s1[j]);
                bhi[j + 4] = (short)h1;
                blo[j + 4] = (short)f2bf_bits(s1[j] - bfbits2f(h1));
            }
            const int ab = (inner * 32 + lk) * 2;
            #pragma unroll
            for (int mf = 0; mf < 2; ++mf) {
                const int ar = arow0 + mf * 16;
                const char* arp = buf + 16384 + ar * 128;
                bf16x8 af = *(const bf16x8*)(arp + (ab ^ aswz));
                acc[mf] = __builtin_amdgcn_mfma_f32_16x16x32_bf16(af, bhi, acc[mf], 0, 0, 0);
                acc[mf] = __builtin_amdgcn_mfma_f32_16x16x32_bf16(af, blo, acc[mf], 0, 0, 0);
            }
        }
        __syncthreads();
    }

    const int rb = (l >> 4) * 4;
    const int nrow = nt * 32 + wrow;
    #pragma unroll
    for (int j = 0; j < 2; ++j) {
        #pragma unroll
        for (int i = 0; i < 4; ++i) {
            const int row = wm * 32 + j * 16 + rb + i;
            float v = acc[j][i];
            if (RELU) v = fmaxf(v, 0.0f);
            if (OUT_BF16)
                OutB[(size_t)e * B_N * N_TOT + (size_t)row * N_TOT + nrow] =
                    __float2bfloat16(v);
            else
                OutF[(size_t)(e * KS + ks) * B_N * N_TOT + (size_t)row * N_TOT + nrow] = v;
        }
    }
}

// out[b,o] = sum_e scores[e] * P[e,b,o]  (R12-verified)
__global__ __launch_bounds__(256)
void reduce_experts(const float* __restrict__ P, const float* __restrict__ scores,
                    float* __restrict__ out)
{
    const int gt = blockIdx.x * 256 + threadIdx.x;
    const int idx = gt * 2;
    float2 acc = {0.0f, 0.0f};
    #pragma unroll
    for (int e = 0; e < E_N; ++e) {
        const float2 v = *(const float2*)(P + (size_t)e * (B_N * OUT_N) + idx);
        const float s = scores[e];
        acc.x += s * v.x;
        acc.y += s * v.y;
    }
    *(float2*)(out + idx) = acc;
}

extern "C" void kernel_launch(void* const* d_in, const int* in_sizes, int n_in,
                              void* d_out, int out_size, void* d_ws, size_t ws_size,
                              hipStream_t stream)
{
    const float* x      = (const float*)d_in[0];
    const float* scores = (const float*)d_in[1];
    const float* delta  = (const float*)d_in[2];
    const float* W1     = (const float*)d_in[3];
    const float* W2     = (const float*)d_in[4];
    const float* W3     = (const float*)d_in[5];
    const float* W4     = (const float*)d_in[6];
    float* out = (float*)d_out;

    char* ws = (char*)d_ws;
    __hip_bfloat16* h1b = (__hip_bfloat16*)(ws + 524288);           // 256 KB
    __hip_bfloat16* h2b = (__hip_bfloat16*)(ws + 786432);           // 2 MB
    __hip_bfloat16* h3b = (__hip_bfloat16*)(ws + 2883584);          // 256 KB
    float* P4 = (float*)(ws + 11534336);                            // 4 MB

    const float* d1 = delta;
    const float* d2 = d1 + (size_t)R_N * IN_N;
    const float* d3 = d2 + (size_t)H_N * R_N;
    const float* d4 = d3 + (size_t)R_N * H_N;

    // L1: no-split-K 16x16 blocks, x f32 converted in-kernel -> h1b direct
    gemm16<IN_N, true, true>
        <<<dim3(512), dim3(256), 0, stream>>>(nullptr, x, W1, d1, h1b);

    // L2: K=512, N=4096, relu -> bf16
    gemm_layer<R_N, H_N, 1, false, true, true, false>
        <<<dim3(E_N * (H_N / 32)), dim3(256), 0, stream>>>(
            h1b, nullptr, W2, d2, nullptr, h2b);

    // L3: no-split-K 16x16 blocks, A = h2b -> h3b direct
    gemm16<H_N, false, false>
        <<<dim3(512), dim3(256), 0, stream>>>(h2b, nullptr, W3, d3, h3b);

    // L4: K=512, N=4096 -> P4 f32
    gemm_layer<R_N, OUT_N, 1, false, false, false, false>
        <<<dim3(E_N * (OUT_N / 32)), dim3(256), 0, stream>>>(
            h3b, nullptr, W4, d4, P4, nullptr);

    // out = sum_e scores[e] * P4[e]
    reduce_experts<<<dim3(B_N * OUT_N / 2 / 256), dim3(256), 0, stream>>>(P4, scores, out);
}

// Round 15
// 55.920 us; speedup vs baseline: 1.1921x; 1.1921x over previous
//
#include <hip/hip_runtime.h>
#include <hip/hip_bf16.h>

#define E_N 4
#define B_N 64
#define IN_N 4096
#define H_N 4096
#define R_N 512
#define OUT_N 4096
#define TOT_N 8388608  // R*IN + H*R + R*H + OUT*R

typedef float f32x4 __attribute__((ext_vector_type(4)));
typedef short bf16x8 __attribute__((ext_vector_type(8)));
typedef unsigned short u16x8 __attribute__((ext_vector_type(8)));

__device__ __forceinline__ unsigned short f2bf_bits(float f) {
    return __builtin_bit_cast(unsigned short, __float2bfloat16(f));
}
__device__ __forceinline__ float bfbits2f(unsigned short u) {
    return __builtin_bit_cast(float, ((unsigned)u) << 16);
}

__device__ __forceinline__ void stage16(const void* g, void* l) {
    __builtin_amdgcn_global_load_lds(
        (const __attribute__((address_space(1))) void*)g,
        (__attribute__((address_space(3))) void*)l, 16, 0, 0);
}

// HW f32 atomic add, fire-and-forget (no return, no CAS loop, no cache flush).
// Atomicity across XCDs resolves at the coherent point; visibility to the NEXT
// dispatch is guaranteed by the kernel boundary. (R8/R13 lesson: fences and
// write-through are catastrophic; a single RMW instruction is not.)
__device__ __forceinline__ void atomic_add_f32(float* p, float v) {
    asm volatile("global_atomic_add_f32 %0, %1, off" :: "v"(p), "v"(v) : "memory");
}

// C[e,b,n] = sum_k A[e?,b,k] * (W[n,k] + D[e,n,k])
// R12 body (verified 48.5 us) with epilogue MODEs:
//   MODE 0: direct bf16 output (optional relu)            -> OutB  (L2)
//   MODE 2: atomic f32 accumulate over split-K            -> OutF  (L1, L3)
//   MODE 3: atomic f32 accumulate of scores[e]*v          -> finalOut (L4)
// ZERO: grid-stride zero of zptr[0..zcount) at kernel start (indep. buffer
// consumed >=2 dispatches later).
template<int K_TOT, int N_TOT, int KS, bool A_SHARED, bool RELU, bool CONV_A,
         int MODE, bool ZERO>
__global__ __launch_bounds__(256, 2)
void gemm_layer(const __hip_bfloat16* __restrict__ A, const float* __restrict__ AF,
                const float* __restrict__ W, const float* __restrict__ D,
                float* __restrict__ OutF, __hip_bfloat16* __restrict__ OutB,
                const float* __restrict__ scores, float* __restrict__ finalOut,
                float* __restrict__ zptr, int zcount)
{
    constexpr int KCH = K_TOT / KS;      // 512 for every layer
    constexpr int NT = N_TOT / 32;
    constexpr int NTILES = KCH / 64;     // 8
    constexpr int BUFSZ = 24576;
    __shared__ __align__(16) char smem[2 * BUFSZ];  // [buf][ Wt 8K | Dt 8K | At 8K ]

    const int bid = blockIdx.x;
    const int tid = threadIdx.x;

    if (ZERO) {
        for (int j = bid * 256 + tid; j < zcount; j += 512 * 256)
            zptr[j] = 0.0f;
    }

    const int ks = bid % KS;
    const int nt = (bid / KS) % NT;
    const int e  = bid / (KS * NT);
    const int l  = tid & 63;
    const int w  = tid >> 6;
    const int wn = w & 1;
    const int wm = w >> 1;
    const int lr = l & 15;
    const int lk = (l >> 4) << 3;

    const float* Wb = W + (size_t)(nt * 32) * K_TOT + ks * KCH;
    const float* Db = D + (size_t)e * TOT_N + (size_t)(nt * 32) * K_TOT + ks * KCH;
    const __hip_bfloat16* Ab = A ? (A + (A_SHARED ? (size_t)0 : (size_t)e * B_N * K_TOT)
                                      + ks * KCH) : nullptr;
    const float* AFb = AF ? (AF + (A_SHARED ? (size_t)0 : (size_t)e * B_N * K_TOT)
                                + ks * KCH) : nullptr;

    // 24 1-KB chunks: q 0-7 Wt, 8-15 Dt, 16-23 At.  q = w + 4*i  (i>=4 <=> A chunk)
    const char* gsrc[6];
    int loff[6], lws[6], kstep[6];
    #pragma unroll
    for (int i = 0; i < 6; ++i) {
        const int q = w + i * 4;
        if (q < 8) {
            const int off = q * 1024 + l * 16;
            const int row = off >> 8, kb = off & 255;
            gsrc[i] = (const char*)(Wb + (size_t)row * K_TOT) + (kb ^ ((row & 7) << 4));
            loff[i] = q * 1024; kstep[i] = 4;
        } else if (q < 16) {
            const int c = q - 8;
            const int off = c * 1024 + l * 16;
            const int row = off >> 8, kb = off & 255;
            gsrc[i] = (const char*)(Db + (size_t)row * K_TOT) + (kb ^ ((row & 7) << 4));
            loff[i] = 8192 + c * 1024; kstep[i] = 4;
        } else {
            const int c = q - 16;
            const int off = c * 1024 + l * 16;
            const int row = off >> 7, kb = off & 127;
            if (CONV_A) {
                gsrc[i] = (const char*)(AFb + (size_t)row * K_TOT) + kb * 2;
                lws[i]  = 16384 + (off & ~127) + (kb ^ ((row & 7) << 4));
                kstep[i] = 4;
            } else {
                gsrc[i] = (const char*)(Ab + (size_t)row * K_TOT) + (kb ^ ((row & 7) << 4));
                loff[i] = 16384 + c * 1024; kstep[i] = 2;
            }
        }
    }

    auto stage_all = [&](int kk, char* b) {
        #pragma unroll
        for (int i = 0; i < 6; ++i) {
            if (CONV_A && i >= 4) {
                const char* src = gsrc[i] + (size_t)kk * 4;
                f32x4 a0 = *(const f32x4*)(src);
                f32x4 a1 = *(const f32x4*)(src + 16);
                u16x8 o;
                #pragma unroll
                for (int j = 0; j < 4; ++j) {
                    o[j]     = f2bf_bits(a0[j]);
                    o[j + 4] = f2bf_bits(a1[j]);
                }
                *(u16x8*)(b + lws[i]) = o;
            } else {
                stage16(gsrc[i] + (size_t)kk * kstep[i], b + loff[i]);
            }
        }
    };

    f32x4 acc[2] = {};
    const int wrow = wn * 16 + lr;
    const int wswz = (wrow & 7) << 4;
    const int arow0 = wm * 32 + lr;
    const int aswz = (arow0 & 7) << 4;

    stage_all(0, smem);
    __syncthreads();

    for (int t = 0; t < NTILES; ++t) {
        if (t + 1 < NTILES)
            stage_all((t + 1) * 64, smem + ((t + 1) & 1) * BUFSZ);

        const char* buf = smem + (t & 1) * BUFSZ;
        #pragma unroll
        for (int inner = 0; inner < 2; ++inner) {
            const int b0 = (inner * 32 + lk) * 4;
            const char* wrp = buf + wrow * 256;
            const char* drp = buf + 8192 + wrow * 256;
            f32x4 w0 = *(const f32x4*)(wrp + ((b0)      ^ wswz));
            f32x4 w1 = *(const f32x4*)(wrp + ((b0 + 16) ^ wswz));
            f32x4 d0 = *(const f32x4*)(drp + ((b0)      ^ wswz));
            f32x4 d1 = *(const f32x4*)(drp + ((b0 + 16) ^ wswz));
            f32x4 s0 = w0 + d0;
            f32x4 s1 = w1 + d1;
            bf16x8 bhi, blo;
            #pragma unroll
            for (int j = 0; j < 4; ++j) {
                unsigned short h0 = f2bf_bits(s0[j]);
                bhi[j] = (short)h0;
                blo[j] = (short)f2bf_bits(s0[j] - bfbits2f(h0));
                unsigned short h1 = f2bf_bits(s1[j]);
                bhi[j + 4] = (short)h1;
                blo[j + 4] = (short)f2bf_bits(s1[j] - bfbits2f(h1));
            }
            const int ab = (inner * 32 + lk) * 2;
            #pragma unroll
            for (int mf = 0; mf < 2; ++mf) {
                const int ar = arow0 + mf * 16;
                const char* arp = buf + 16384 + ar * 128;
                bf16x8 af = *(const bf16x8*)(arp + (ab ^ aswz));
                acc[mf] = __builtin_amdgcn_mfma_f32_16x16x32_bf16(af, bhi, acc[mf], 0, 0, 0);
                acc[mf] = __builtin_amdgcn_mfma_f32_16x16x32_bf16(af, blo, acc[mf], 0, 0, 0);
            }
        }
        __syncthreads();
    }

    // C/D layout: col = l&15 (== nrow), row(frag) = (l>>4)*4 + i
    const int rb = (l >> 4) * 4;
    const int nrow = nt * 32 + wrow;
    const float se = (MODE == 3) ? scores[e] : 0.0f;
    #pragma unroll
    for (int j = 0; j < 2; ++j) {
        #pragma unroll
        for (int i = 0; i < 4; ++i) {
            const int row = wm * 32 + j * 16 + rb + i;
            float v = acc[j][i];
            if (RELU) v = fmaxf(v, 0.0f);
            if (MODE == 0) {
                OutB[(size_t)e * B_N * N_TOT + (size_t)row * N_TOT + nrow] =
                    __float2bfloat16(v);
            } else if (MODE == 2) {
                atomic_add_f32(OutF + (size_t)e * B_N * N_TOT
                                    + (size_t)row * N_TOT + nrow, v);
            } else {  // MODE 3
                atomic_add_f32(finalOut + (size_t)row * N_TOT + nrow, se * v);
            }
        }
    }
}

extern "C" void kernel_launch(void* const* d_in, const int* in_sizes, int n_in,
                              void* d_out, int out_size, void* d_ws, size_t ws_size,
                              hipStream_t stream)
{
    const float* x      = (const float*)d_in[0];
    const float* scores = (const float*)d_in[1];
    const float* delta  = (const float*)d_in[2];
    const float* W1     = (const float*)d_in[3];
    const float* W2     = (const float*)d_in[4];
    const float* W3     = (const float*)d_in[5];
    const float* W4     = (const float*)d_in[6];
    float* out = (float*)d_out;

    char* ws = (char*)d_ws;
    float* h1f = (float*)(ws);                        // 512 KB f32 [4][64][512]
    float* h3f = (float*)(ws + 524288);               // 512 KB f32 [4][64][512]
    __hip_bfloat16* h2b = (__hip_bfloat16*)(ws + 1048576);   // 2 MB bf16 [4][64][4096]

    const float* d1 = delta;
    const float* d2 = d1 + (size_t)R_N * IN_N;
    const float* d3 = d2 + (size_t)H_N * R_N;
    const float* d4 = d3 + (size_t)R_N * H_N;

    // h1f must be zero before L1's atomic accumulation (every launch/replay)
    hipMemsetAsync(h1f, 0, 524288, stream);

    // L1: K=4096, N=512, KS=8, CONV_A(x f32) -> atomic h1f; zeroes h3f for L3
    gemm_layer<IN_N, R_N, 8, true, false, true, 2, true>
        <<<dim3(E_N * (R_N / 32) * 8), dim3(256), 0, stream>>>(
            nullptr, x, W1, d1, h1f, nullptr, nullptr, nullptr,
            h3f, E_N * B_N * R_N);

    // L2: K=512, N=4096, CONV_A(h1f f32), relu -> h2b bf16; zeroes out for L4
    gemm_layer<R_N, H_N, 1, false, true, true, 0, true>
        <<<dim3(E_N * (H_N / 32)), dim3(256), 0, stream>>>(
            nullptr, h1f, W2, d2, nullptr, h2b, nullptr, nullptr,
            out, B_N * OUT_N);

    // L3: K=4096, N=512, KS=8, A=h2b bf16 -> atomic h3f
    gemm_layer<H_N, R_N, 8, false, false, false, 2, false>
        <<<dim3(E_N * (R_N / 32) * 8), dim3(256), 0, stream>>>(
            h2b, nullptr, W3, d3, h3f, nullptr, nullptr, nullptr,
            nullptr, 0);

    // L4: K=512, N=4096, CONV_A(h3f f32) -> atomic scores[e]*v into out
    gemm_layer<R_N, OUT_N, 1, false, false, true, 3, false>
        <<<dim3(E_N * (OUT_N / 32)), dim3(256), 0, stream>>>(
            nullptr, h3f, W4, d4, nullptr, nullptr, scores, out,
            nullptr, 0);
}